// Round 2
// baseline (447.273 us; speedup 1.0000x reference)
//
#include <hip/hip_runtime.h>
#include <hip/hip_bf16.h>

#define B_ 4
#define N_ 1024
#define NB_ 32
#define C_ 384
#define CZ_ 128
#define NSITES (B_ * N_)   // 4096
#define EPSV 1e-6f
#define PAD 40             // u16 per LDS row: 32 data + 8 pad -> 2-way-only bank aliasing (free)
#define SPB 4              // sites per block
#define MROWS 128          // SPB * NB_
#define THREADS 512

typedef unsigned short u16;
typedef unsigned int u32;
typedef __bf16 bf16x8 __attribute__((ext_vector_type(8)));
typedef float f32x4 __attribute__((ext_vector_type(4)));

__device__ __forceinline__ u16 f2bf(float f) {
    return __builtin_bit_cast(u16, __float2bfloat16(f));
}
__device__ __forceinline__ float bfbits2f(u16 u) {
    union { float f; u32 i; } x;
    x.i = ((u32)u) << 16;
    return x.f;
}

// Transpose weights to bf16: Wts[d][c] = bf16(W_s[c][d]) (384x384), Wtz[d][z] = bf16(W_z[z][d]) (384x128)
__global__ void prep_weights(const float* __restrict__ Ws, const float* __restrict__ Wz,
                             u16* __restrict__ Wts, u16* __restrict__ Wtz) {
    int idx = blockIdx.x * 256 + threadIdx.x;
    if (idx < C_ * C_) {
        int d = idx / C_, c = idx % C_;
        Wts[idx] = f2bf(Ws[c * C_ + d]);
    } else {
        int j = idx - C_ * C_;
        if (j < C_ * CZ_) {
            int d = j / CZ_, z = j % CZ_;
            Wtz[j] = f2bf(Wz[z * C_ + d]);
        }
    }
}

// Prefetch registers for one K-chunk: W = 3x16B (384 rows x 4 segs = 1536 segs / 512 thr),
// A = 8 floats (128 rows x 4 segs = 512 segs / 512 thr).
struct Stage {
    uint4 w0, w1, w2;
    float4 a0, a1;
};

__device__ __forceinline__ void issue_stage(Stage& st, const u16* __restrict__ Wt, int kdim,
                                            const float* __restrict__ A, long rowbase,
                                            int kc, int tid) {
    // A first: HBM stream, longest latency
    int ar = tid >> 2, ag = tid & 3;
    const float* src = A + (rowbase + ar) * (long)kdim + kc + ag * 8;
    st.a0 = *reinterpret_cast<const float4*>(src);
    st.a1 = *reinterpret_cast<const float4*>(src + 4);
    // W: L2-resident (shared by all blocks)
    int s = tid;
    st.w0 = *reinterpret_cast<const uint4*>(Wt + (s >> 2) * kdim + kc + (s & 3) * 8);
    s = tid + 512;
    st.w1 = *reinterpret_cast<const uint4*>(Wt + (s >> 2) * kdim + kc + (s & 3) * 8);
    s = tid + 1024;
    st.w2 = *reinterpret_cast<const uint4*>(Wt + (s >> 2) * kdim + kc + (s & 3) * 8);
}

__device__ __forceinline__ void commit_stage(const Stage& st, u16* ldsW, u16* ldsA, int tid) {
    int s = tid;
    *reinterpret_cast<uint4*>(&ldsW[(s >> 2) * PAD + (s & 3) * 8]) = st.w0;
    s = tid + 512;
    *reinterpret_cast<uint4*>(&ldsW[(s >> 2) * PAD + (s & 3) * 8]) = st.w1;
    s = tid + 1024;
    *reinterpret_cast<uint4*>(&ldsW[(s >> 2) * PAD + (s & 3) * 8]) = st.w2;
    int ar = tid >> 2, ag = tid & 3;
    uint4 h;
    h.x = ((u32)f2bf(st.a0.y) << 16) | f2bf(st.a0.x);
    h.y = ((u32)f2bf(st.a0.w) << 16) | f2bf(st.a0.z);
    h.z = ((u32)f2bf(st.a1.y) << 16) | f2bf(st.a1.x);
    h.w = ((u32)f2bf(st.a1.w) << 16) | f2bf(st.a1.z);
    *reinterpret_cast<uint4*>(&ldsA[ar * PAD + ag * 8]) = h;
}

__device__ __forceinline__ void compute_chunk(const u16* ldsW, const u16* ldsA,
                                              f32x4 (&acc)[4][6],
                                              int mg, int colbase, int ln, int q) {
    bf16x8 a[4];
    #pragma unroll
    for (int mt = 0; mt < 4; ++mt)
        a[mt] = *reinterpret_cast<const bf16x8*>(&ldsA[(mg * 64 + mt * 16 + ln) * PAD + q * 8]);
    #pragma unroll
    for (int nt = 0; nt < 6; ++nt) {
        bf16x8 b = *reinterpret_cast<const bf16x8*>(&ldsW[(colbase + nt * 16 + ln) * PAD + q * 8]);
        #pragma unroll
        for (int mt = 0; mt < 4; ++mt)
            acc[mt][nt] = __builtin_amdgcn_mfma_f32_16x16x32_bf16(a[mt], b, acc[mt][nt], 0, 0, 0);
    }
}

// Block = 512 thr (8 waves), 4 sites (M=128 neighbor rows), N=384.
// Wave (mg, ns): rows [mg*64, +64), cols [ns*96, +96).
__global__ __launch_bounds__(THREADS, 2)
void fused_msg_kernel(const float* __restrict__ s_i,
                      const float* __restrict__ s_ij,
                      const float* __restrict__ m_ij,
                      const float* __restrict__ z_ij,
                      const u16* __restrict__ Wts,
                      const u16* __restrict__ Wtz,
                      const float* __restrict__ gamma,
                      const float* __restrict__ beta,
                      float* __restrict__ out) {
    __shared__ u16 ldsW[C_ * PAD];          // 30720 B (single buffer, W chunk)
    __shared__ u16 ldsA[2][MROWS * PAD];    // 20480 B (double buffer, A chunk)
    __shared__ float lds_si[SPB * C_];      //  6144 B
    __shared__ float lds_m[MROWS];          //   512 B
    __shared__ float lds_snew[SPB * C_];    //  6144 B   total 64000 B

    const int tid = threadIdx.x;
    const int wave = tid >> 6;
    const int lane = tid & 63;
    const int q = lane >> 4;
    const int ln = lane & 15;
    const int mg = wave >> 2;        // row half
    const int colbase = (wave & 3) * 96;

    const int site0 = blockIdx.x * SPB;
    const long rowbase = (long)site0 * NB_;

    for (int i = tid; i < SPB * C_; i += THREADS)
        lds_si[i] = s_i[(long)site0 * C_ + i];
    if (tid < MROWS) lds_m[tid] = m_ij[rowbase + tid];

    const f32x4 ZERO = {0.f, 0.f, 0.f, 0.f};
    f32x4 acc[4][6];
    #pragma unroll
    for (int mt = 0; mt < 4; ++mt)
        #pragma unroll
        for (int nt = 0; nt < 6; ++nt)
            acc[mt][nt] = ZERO;

    Stage st;

    // ---------------- Phase 1: gate = z_ij @ W_z  (K = 128, 4 chunks) ----------------
    {
        const int NK = CZ_ / 32;
        issue_stage(st, Wtz, CZ_, z_ij, rowbase, 0, tid);
        commit_stage(st, ldsW, ldsA[0], tid);
        __syncthreads();
        #pragma unroll 2
        for (int c = 0; c < NK; ++c) {
            if (c + 1 < NK) issue_stage(st, Wtz, CZ_, z_ij, rowbase, (c + 1) * 32, tid);
            compute_chunk(ldsW, ldsA[c & 1], acc, mg, colbase, ln, q);
            __syncthreads();
            if (c + 1 < NK) {
                commit_stage(st, ldsW, ldsA[(c + 1) & 1], tid);
                __syncthreads();
            }
        }
    }

    // fold mask into gate, pack to bf16 pairs, free accumulators
    u32 gateb[4][6][2];
    #pragma unroll
    for (int mt = 0; mt < 4; ++mt) {
        int rb = mg * 64 + mt * 16 + q * 4;
        float m0 = lds_m[rb + 0];
        float m1 = lds_m[rb + 1];
        float m2 = lds_m[rb + 2];
        float m3 = lds_m[rb + 3];
        #pragma unroll
        for (int nt = 0; nt < 6; ++nt) {
            gateb[mt][nt][0] = ((u32)f2bf(acc[mt][nt][1] * m1) << 16) | f2bf(acc[mt][nt][0] * m0);
            gateb[mt][nt][1] = ((u32)f2bf(acc[mt][nt][3] * m3) << 16) | f2bf(acc[mt][nt][2] * m2);
            acc[mt][nt] = ZERO;
        }
    }

    // ---------------- Phase 2: s_proj = s_ij @ W_s  (K = 384, 12 chunks) ----------------
    {
        const int NK = C_ / 32;
        issue_stage(st, Wts, C_, s_ij, rowbase, 0, tid);
        commit_stage(st, ldsW, ldsA[0], tid);
        __syncthreads();
        #pragma unroll 2
        for (int c = 0; c < NK; ++c) {
            if (c + 1 < NK) issue_stage(st, Wts, C_, s_ij, rowbase, (c + 1) * 32, tid);
            compute_chunk(ldsW, ldsA[c & 1], acc, mg, colbase, ln, q);
            __syncthreads();
            if (c + 1 < NK) {
                commit_stage(st, ldsW, ldsA[(c + 1) & 1], tid);
                __syncthreads();
            }
        }
    }

    // ---------------- Epilogue: msg + neighbor reduction ----------------
    // acc row = mg*64 + mt*16 + q*4 + r ; col = colbase + nt*16 + ln
    #pragma unroll
    for (int sl = 0; sl < 2; ++sl) {
        int site = mg * 2 + sl;
        #pragma unroll
        for (int nt = 0; nt < 6; ++nt) {
            int col = colbase + nt * 16 + ln;
            float si = lds_si[site * C_ + col];
            float p = 0.f;
            #pragma unroll
            for (int mh = 0; mh < 2; ++mh) {
                int mt = sl * 2 + mh;
                #pragma unroll
                for (int r = 0; r < 4; ++r) {
                    float g = bfbits2f((u16)(gateb[mt][nt][r >> 1] >> ((r & 1) * 16)));
                    p += (acc[mt][nt][r] - si) * g;
                }
            }
            p += __shfl_xor(p, 16, 64);
            p += __shfl_xor(p, 32, 64);
            if (q == 0) lds_snew[site * C_ + col] = p;
        }
    }
    __syncthreads();

    // ---------------- LayerNorm: wave w (<4) handles site w ----------------
    if (wave < SPB) {
        const int site = wave;
        float v[6];
        float sum = 0.f, sumsq = 0.f;
        #pragma unroll
        for (int i = 0; i < 6; ++i) {
            v[i] = lds_snew[site * C_ + lane + i * 64];
            sum += v[i];
            sumsq += v[i] * v[i];
        }
        #pragma unroll
        for (int off = 32; off >= 1; off >>= 1) {
            sum += __shfl_xor(sum, off, 64);
            sumsq += __shfl_xor(sumsq, off, 64);
        }
        float mu = sum * (1.f / C_);
        float var = sumsq * (1.f / C_) - mu * mu;
        float rs = rsqrtf(var + EPSV);
        #pragma unroll
        for (int i = 0; i < 6; ++i) {
            int col = lane + i * 64;
            out[(long)(site0 + site) * C_ + col] = (v[i] - mu) * rs * gamma[col] + beta[col];
        }
    }
}

extern "C" void kernel_launch(void* const* d_in, const int* in_sizes, int n_in,
                              void* d_out, int out_size, void* d_ws, size_t ws_size,
                              hipStream_t stream) {
    (void)in_sizes; (void)n_in; (void)out_size; (void)ws_size;
    const float* s_i   = (const float*)d_in[0];
    const float* s_ij  = (const float*)d_in[1];
    const float* m_ij  = (const float*)d_in[2];
    const float* z_ij  = (const float*)d_in[3];
    const float* W_s   = (const float*)d_in[4];
    const float* W_z   = (const float*)d_in[5];
    const float* gamma = (const float*)d_in[6];
    const float* beta  = (const float*)d_in[7];
    float* out = (float*)d_out;

    u16* wts = (u16*)d_ws;             // 384*384 bf16 = 294912 B
    u16* wtz = wts + C_ * C_;          // 384*128 bf16 =  98304 B  (total 393216 B of ws)

    int prep_elems = C_ * C_ + C_ * CZ_;
    prep_weights<<<(prep_elems + 255) / 256, 256, 0, stream>>>(W_s, W_z, wts, wtz);
    fused_msg_kernel<<<NSITES / SPB, THREADS, 0, stream>>>(s_i, s_ij, m_ij, z_ij, wts, wtz,
                                                           gamma, beta, out);
}

// Round 3
// 438.660 us; speedup vs baseline: 1.0196x; 1.0196x over previous
//
#include <hip/hip_runtime.h>
#include <hip/hip_bf16.h>

#define B_ 4
#define N_ 1024
#define NB_ 32
#define C_ 384
#define CZ_ 128
#define NSITES (B_ * N_)   // 4096
#define EPSV 1e-6f
#define PAD 40             // u16 per LDS row: 32 data + 8 pad
#define SPB 2              // sites per block
#define MR 64              // neighbor rows per block
#define THREADS 512

typedef unsigned short u16;
typedef unsigned int u32;
typedef __bf16 bf16x8 __attribute__((ext_vector_type(8)));
typedef float f32x4 __attribute__((ext_vector_type(4)));

__device__ __forceinline__ u16 f2bf(float f) {
    return __builtin_bit_cast(u16, __float2bfloat16(f));
}
__device__ __forceinline__ u32 pk2(float lo, float hi) {
    return ((u32)f2bf(hi) << 16) | f2bf(lo);
}
__device__ __forceinline__ float bfbits2f(u16 u) {
    union { float f; u32 i; } x;
    x.i = ((u32)u) << 16;
    return x.f;
}

// Wts[d][c] = bf16(W_s[c][d]) (384x384), Wtz[d][z] = bf16(W_z[z][d]) (384x128)
__global__ void prep_weights(const float* __restrict__ Ws, const float* __restrict__ Wz,
                             u16* __restrict__ Wts, u16* __restrict__ Wtz) {
    int idx = blockIdx.x * 256 + threadIdx.x;
    if (idx < C_ * C_) {
        int d = idx / C_, c = idx % C_;
        Wts[idx] = f2bf(Ws[c * C_ + d]);
    } else {
        int j = idx - C_ * C_;
        if (j < C_ * CZ_) {
            int d = j / CZ_, z = j % CZ_;
            Wtz[j] = f2bf(Wz[z * C_ + d]);
        }
    }
}

// Block = 512 thr (8 waves), 2 sites (M=64 rows), N=384.
// Wave (mg, ns): mg = site half (32 rows), ns = 96-col strip.
// Per wave: acc 2x6 f32x4 (48) + gateb 24 + staging 16 -> fits 128-reg cap
// -> 4 waves/SIMD -> 2 blocks/CU co-resident (the R2 fix).
__global__ __launch_bounds__(THREADS, 4)
void fused_msg_kernel(const float* __restrict__ s_i,
                      const float* __restrict__ s_ij,
                      const float* __restrict__ m_ij,
                      const float* __restrict__ z_ij,
                      const u16* __restrict__ Wts,
                      const u16* __restrict__ Wtz,
                      const float* __restrict__ gamma,
                      const float* __restrict__ beta,
                      float* __restrict__ out) {
    __shared__ u16 ldsW[2][C_ * PAD];   // 2 x 30720 B
    __shared__ u16 ldsA[2][MR * PAD];   // 2 x  5120 B
    __shared__ float lds_snew[SPB * C_];//      3072 B   total 74752 B -> 2 blocks/CU

    const int tid = threadIdx.x;
    const int wave = tid >> 6;
    const int lane = tid & 63;
    const int q = lane >> 4;
    const int ln = lane & 15;
    const int mg = wave >> 2;            // site within the pair
    const int cb = (wave & 3) * 96;      // column strip base

    const int site0 = blockIdx.x * SPB;
    const long rowbase = (long)site0 * NB_;

    // staging maps (constant per thread)
    const int arow = tid >> 3, aseg = tid & 7;      // A: row 0..63, 4 floats at k=aseg*4
    const int wrow = tid >> 2, wseg = tid & 3;      // W: col 0..127 (+128,+256), 8 bf16 at k=wseg*8
    const int la_w = arow * PAD + aseg * 4;
    const int lw_w = wrow * PAD + wseg * 8;

    const float mv = m_ij[rowbase + lane];          // per-lane neighbor mask

    const f32x4 ZERO = {0.f, 0.f, 0.f, 0.f};
    f32x4 acc[2][6];
    #pragma unroll
    for (int mt = 0; mt < 2; ++mt)
        #pragma unroll
        for (int nt = 0; nt < 6; ++nt)
            acc[mt][nt] = ZERO;

    float4 ra;
    uint4 rw0, rw1, rw2;

    // -------- Phase 1: gate = z @ Wz (kd=128, NK=4) --------
    {
        const int kd = CZ_;
        const float* ap = z_ij + (rowbase + arow) * kd + aseg * 4;
        const u16* wp = Wtz + wrow * kd + wseg * 8;
        const int ws1 = 128 * kd, ws2 = 256 * kd;

        ra = *reinterpret_cast<const float4*>(ap);
        rw0 = *reinterpret_cast<const uint4*>(wp);
        rw1 = *reinterpret_cast<const uint4*>(wp + ws1);
        rw2 = *reinterpret_cast<const uint4*>(wp + ws2);
        ap += 32; wp += 32;
        {
            uint2 a2 = {pk2(ra.x, ra.y), pk2(ra.z, ra.w)};
            *reinterpret_cast<uint2*>(&ldsA[0][la_w]) = a2;
            *reinterpret_cast<uint4*>(&ldsW[0][lw_w]) = rw0;
            *reinterpret_cast<uint4*>(&ldsW[0][lw_w + 128 * PAD]) = rw1;
            *reinterpret_cast<uint4*>(&ldsW[0][lw_w + 256 * PAD]) = rw2;
        }
        __syncthreads();

        #pragma unroll 2
        for (int c = 0; c < 4; ++c) {
            if (c + 1 < 4) {
                ra = *reinterpret_cast<const float4*>(ap);
                rw0 = *reinterpret_cast<const uint4*>(wp);
                rw1 = *reinterpret_cast<const uint4*>(wp + ws1);
                rw2 = *reinterpret_cast<const uint4*>(wp + ws2);
                ap += 32; wp += 32;
            }
            const u16* lA = ldsA[c & 1];
            const u16* lW = ldsW[c & 1];
            bf16x8 a0 = *reinterpret_cast<const bf16x8*>(&lA[(mg * 32 + ln) * PAD + q * 8]);
            bf16x8 a1 = *reinterpret_cast<const bf16x8*>(&lA[(mg * 32 + 16 + ln) * PAD + q * 8]);
            #pragma unroll
            for (int nt = 0; nt < 6; ++nt) {
                bf16x8 b = *reinterpret_cast<const bf16x8*>(&lW[(cb + nt * 16 + ln) * PAD + q * 8]);
                acc[0][nt] = __builtin_amdgcn_mfma_f32_16x16x32_bf16(a0, b, acc[0][nt], 0, 0, 0);
                acc[1][nt] = __builtin_amdgcn_mfma_f32_16x16x32_bf16(a1, b, acc[1][nt], 0, 0, 0);
            }
            if (c + 1 < 4) {
                int nb = (c + 1) & 1;
                uint2 a2 = {pk2(ra.x, ra.y), pk2(ra.z, ra.w)};
                *reinterpret_cast<uint2*>(&ldsA[nb][la_w]) = a2;
                *reinterpret_cast<uint4*>(&ldsW[nb][lw_w]) = rw0;
                *reinterpret_cast<uint4*>(&ldsW[nb][lw_w + 128 * PAD]) = rw1;
                *reinterpret_cast<uint4*>(&ldsW[nb][lw_w + 256 * PAD]) = rw2;
            }
            __syncthreads();
        }
    }

    // fold mask into gate, pack bf16, zero acc
    u32 gateb[2][6][2];
    #pragma unroll
    for (int mt = 0; mt < 2; ++mt) {
        int rb = mg * 32 + mt * 16 + q * 4;
        float m0 = __shfl(mv, rb + 0, 64);
        float m1 = __shfl(mv, rb + 1, 64);
        float m2 = __shfl(mv, rb + 2, 64);
        float m3 = __shfl(mv, rb + 3, 64);
        #pragma unroll
        for (int nt = 0; nt < 6; ++nt) {
            gateb[mt][nt][0] = pk2(acc[mt][nt][0] * m0, acc[mt][nt][1] * m1);
            gateb[mt][nt][1] = pk2(acc[mt][nt][2] * m2, acc[mt][nt][3] * m3);
            acc[mt][nt] = ZERO;
        }
    }

    // -------- Phase 2: s_proj = s @ Ws (kd=384, NK=12) --------
    {
        const int kd = C_;
        const float* ap = s_ij + (rowbase + arow) * kd + aseg * 4;
        const u16* wp = Wts + wrow * kd + wseg * 8;
        const int ws1 = 128 * kd, ws2 = 256 * kd;

        ra = *reinterpret_cast<const float4*>(ap);
        rw0 = *reinterpret_cast<const uint4*>(wp);
        rw1 = *reinterpret_cast<const uint4*>(wp + ws1);
        rw2 = *reinterpret_cast<const uint4*>(wp + ws2);
        ap += 32; wp += 32;
        {
            uint2 a2 = {pk2(ra.x, ra.y), pk2(ra.z, ra.w)};
            *reinterpret_cast<uint2*>(&ldsA[0][la_w]) = a2;
            *reinterpret_cast<uint4*>(&ldsW[0][lw_w]) = rw0;
            *reinterpret_cast<uint4*>(&ldsW[0][lw_w + 128 * PAD]) = rw1;
            *reinterpret_cast<uint4*>(&ldsW[0][lw_w + 256 * PAD]) = rw2;
        }
        __syncthreads();

        #pragma unroll 2
        for (int c = 0; c < 12; ++c) {
            if (c + 1 < 12) {
                ra = *reinterpret_cast<const float4*>(ap);
                rw0 = *reinterpret_cast<const uint4*>(wp);
                rw1 = *reinterpret_cast<const uint4*>(wp + ws1);
                rw2 = *reinterpret_cast<const uint4*>(wp + ws2);
                ap += 32; wp += 32;
            }
            const u16* lA = ldsA[c & 1];
            const u16* lW = ldsW[c & 1];
            bf16x8 a0 = *reinterpret_cast<const bf16x8*>(&lA[(mg * 32 + ln) * PAD + q * 8]);
            bf16x8 a1 = *reinterpret_cast<const bf16x8*>(&lA[(mg * 32 + 16 + ln) * PAD + q * 8]);
            #pragma unroll
            for (int nt = 0; nt < 6; ++nt) {
                bf16x8 b = *reinterpret_cast<const bf16x8*>(&lW[(cb + nt * 16 + ln) * PAD + q * 8]);
                acc[0][nt] = __builtin_amdgcn_mfma_f32_16x16x32_bf16(a0, b, acc[0][nt], 0, 0, 0);
                acc[1][nt] = __builtin_amdgcn_mfma_f32_16x16x32_bf16(a1, b, acc[1][nt], 0, 0, 0);
            }
            if (c + 1 < 12) {
                int nb = (c + 1) & 1;
                uint2 a2 = {pk2(ra.x, ra.y), pk2(ra.z, ra.w)};
                *reinterpret_cast<uint2*>(&ldsA[nb][la_w]) = a2;
                *reinterpret_cast<uint4*>(&ldsW[nb][lw_w]) = rw0;
                *reinterpret_cast<uint4*>(&ldsW[nb][lw_w + 128 * PAD]) = rw1;
                *reinterpret_cast<uint4*>(&ldsW[nb][lw_w + 256 * PAD]) = rw2;
            }
            __syncthreads();
        }
    }

    // -------- Epilogue: msg + neighbor reduction --------
    // acc row = mg*32 + mt*16 + q*4 + r  (all rows of site mg); col = cb + nt*16 + ln
    #pragma unroll
    for (int nt = 0; nt < 6; ++nt) {
        int col = cb + nt * 16 + ln;
        float si = s_i[(long)(site0 + mg) * C_ + col];
        float p = 0.f;
        #pragma unroll
        for (int mt = 0; mt < 2; ++mt) {
            #pragma unroll
            for (int r = 0; r < 4; ++r) {
                float g = bfbits2f((u16)(gateb[mt][nt][r >> 1] >> ((r & 1) * 16)));
                p += (acc[mt][nt][r] - si) * g;
            }
        }
        p += __shfl_xor(p, 16, 64);
        p += __shfl_xor(p, 32, 64);
        if (q == 0) lds_snew[mg * C_ + col] = p;
    }
    __syncthreads();

    // -------- LayerNorm: wave 0 -> site0, wave 1 -> site1 --------
    if (wave < SPB) {
        const int site = wave;
        float v[6];
        float sum = 0.f, sumsq = 0.f;
        #pragma unroll
        for (int i = 0; i < 6; ++i) {
            v[i] = lds_snew[site * C_ + lane + i * 64];
            sum += v[i];
            sumsq += v[i] * v[i];
        }
        #pragma unroll
        for (int off = 32; off >= 1; off >>= 1) {
            sum += __shfl_xor(sum, off, 64);
            sumsq += __shfl_xor(sumsq, off, 64);
        }
        float mu = sum * (1.f / C_);
        float var = sumsq * (1.f / C_) - mu * mu;
        float rs = rsqrtf(var + EPSV);
        #pragma unroll
        for (int i = 0; i < 6; ++i) {
            int col = lane + i * 64;
            out[(long)(site0 + site) * C_ + col] = (v[i] - mu) * rs * gamma[col] + beta[col];
        }
    }
}

extern "C" void kernel_launch(void* const* d_in, const int* in_sizes, int n_in,
                              void* d_out, int out_size, void* d_ws, size_t ws_size,
                              hipStream_t stream) {
    (void)in_sizes; (void)n_in; (void)out_size; (void)ws_size;
    const float* s_i   = (const float*)d_in[0];
    const float* s_ij  = (const float*)d_in[1];
    const float* m_ij  = (const float*)d_in[2];
    const float* z_ij  = (const float*)d_in[3];
    const float* W_s   = (const float*)d_in[4];
    const float* W_z   = (const float*)d_in[5];
    const float* gamma = (const float*)d_in[6];
    const float* beta  = (const float*)d_in[7];
    float* out = (float*)d_out;

    u16* wts = (u16*)d_ws;             // 384*384 bf16
    u16* wtz = wts + C_ * C_;          // 384*128 bf16

    int prep_elems = C_ * C_ + C_ * CZ_;
    prep_weights<<<(prep_elems + 255) / 256, 256, 0, stream>>>(W_s, W_z, wts, wtz);
    fused_msg_kernel<<<NSITES / SPB, THREADS, 0, stream>>>(s_i, s_ij, m_ij, z_ij, wts, wtz,
                                                           gamma, beta, out);
}